// Round 7
// baseline (27.915 us; speedup 1.0000x reference)
//
#include <hip/hip_runtime.h>

#define IN_SIZE 11
#define HID 16
#define FEAT 18
#define TSTEPS 18
#define SSTRIDE 128   // sample stride: window = 128 elements = 512 B (int4/lane x 32)

__device__ __forceinline__ float fast_rcp(float v) { return __builtin_amdgcn_rcpf(v); }

// broadcast a float from a fixed lane via v_readlane (SGPR path, no DS)
__device__ __forceinline__ float rl(float v, int lane) {
    return __int_as_float(__builtin_amdgcn_readlane(__float_as_int(v), lane));
}

// ---------------------------------------------------------------------------
// Kernel A: sample batch at stride 128 into a 250 KB table (L2-resident for
// the main kernel). Branch-free, one load + one store per thread.
// ---------------------------------------------------------------------------
__global__ __launch_bounds__(256)
void sample_batch(const int* __restrict__ batch, int* __restrict__ tbl,
                  int E, int S)
{
    const int i = blockIdx.x * blockDim.x + threadIdx.x;
    if (i < S) tbl[i] = batch[(long)i * SSTRIDE];
}

// ---------------------------------------------------------------------------
// Main kernel: one WAVE per graph. Lane wl owns gate row wl (r=wl>>4, u=wl&15).
// Dual lower_bound via 32-lane halves over the SAMPLE TABLE (4 L2-hot rounds),
// then ONE scattered HBM round: int4-scan of the 128-element bracket window.
// ---------------------------------------------------------------------------
extern "C" __global__ __launch_bounds__(256, 4)
void tgnn_lstm_fused(const float* __restrict__ x,
                     const float* __restrict__ W_ih,
                     const float* __restrict__ W_hh,
                     const float* __restrict__ b_ih,
                     const float* __restrict__ b_hh,
                     const float* __restrict__ W_fc,
                     const float* __restrict__ b_fc,
                     const int* __restrict__ edge_index,
                     const int* __restrict__ edge_attr,
                     const int* __restrict__ batch,
                     const int* __restrict__ tbl,
                     float* __restrict__ out,
                     int E, int B, int S)
{
    const int wl  = threadIdx.x & 63;
    const int g   = (blockIdx.x * blockDim.x + threadIdx.x) >> 6;  // wave id = graph
    const int u   = wl & 15;
    const int r   = wl >> 4;
    const int row = wl;

    // ---- per-lane weights (issued first; latency overlaps the search) ----
    float wih[IN_SIZE], whh[HID];
#pragma unroll
    for (int k = 0; k < IN_SIZE; ++k) wih[k] = W_ih[row * FEAT + k];
#pragma unroll
    for (int v = 0; v < HID; ++v) whh[v] = W_hh[row * HID + v];
    const float bias = b_ih[row] + b_hh[row];
    const float wfc  = W_fc[row];
    const float bfc  = b_fc[r];

    // ---- dual lower_bound over the sample table (lanes<32 -> g, >=32 -> g+1) ----
    const int vt  = g + (wl >> 5);
    const int l32 = wl & 31;
    int lo = 0, hi = S;
    int n = hi - lo;
    while (n > 32) {
        int p = lo + (int)(((unsigned)n * (unsigned)l32) >> 5);
        const int bv = tbl[p];
        const unsigned long long bal = __ballot(bv < vt);
        const int myc = (wl < 32) ? __popc((unsigned)bal)
                                  : __popc((unsigned)(bal >> 32));
        const int nlo = myc ? (lo + (int)(((unsigned)n * (unsigned)(myc - 1)) >> 5) + 1) : lo;
        const int nhi = (myc < 32) ? (lo + (int)(((unsigned)n * (unsigned)myc) >> 5)) : hi;
        lo = nlo; hi = nhi; n = hi - lo;
    }
    {   // final table scan over [lo, lo+n), n <= 32
        int p = lo + l32; if (p > S - 1) p = S - 1;
        const bool lt = (l32 < n) && (tbl[p] < vt);
        const unsigned long long bal = __ballot(lt);
        const int myc = (wl < 32) ? __popc((unsigned)bal)
                                  : __popc((unsigned)(bal >> 32));
        lo += myc;                       // = istar = lower_bound(tbl, vt)
    }
    // ---- ONE HBM round: scan the 128-element bracket window with int4/lane ----
    // lb(batch, vt) is in (SSTRIDE*(istar-1), SSTRIDE*istar]; window fully read.
    const int istar = lo;
    const int base  = (istar > 0) ? (istar - 1) * SSTRIDE : 0;
    int4 q;
    {
        const int4* bp = reinterpret_cast<const int4*>(batch + base);
        q = bp[l32];                     // base + 4*l32 .. +3  (always in-bounds)
    }
    int cown = (q.x < vt) + (q.y < vt) + (q.z < vt) + (q.w < vt);
#pragma unroll
    for (int m = 16; m >= 1; m >>= 1) cown += __shfl_xor(cown, m, 32);
    const int lb = (istar == 0) ? 0 : (base + cown);

    const int f0 = __builtin_amdgcn_readlane(lb, 0);    // first edge of g
    const int f1 = __builtin_amdgcn_readlane(lb, 32);   // first edge of g+1
    int cnt = f1 - f0;
    cnt = (cnt < 0) ? 0 : ((cnt > TSTEPS) ? TSTEPS : cnt);

    // ---- edge fetch: lane t (t<18) loads step t's ids + attr (one round) ----
    int n1 = 0, n2 = 0, ea = 0;
    if (wl < TSTEPS) {
        int j = f0 + wl;
        if (j > E - 1) j = E - 1;
        n1 = edge_index[j];
        n2 = edge_index[E + j];
        ea = edge_attr[j];               // in [0,7) even when clamped
    }

    // ---- x gather: lane t holds step t's 11 summed features (one round) ----
    float f[IN_SIZE];
    {
        const float* xa = x + (long)n1 * IN_SIZE;
        const float* xb = x + (long)n2 * IN_SIZE;
#pragma unroll
        for (int k = 0; k < IN_SIZE; ++k) f[k] = xa[k] + xb[k];
    }
    if (wl >= cnt) {                     // invalid steps AND lanes >= 18
#pragma unroll
        for (int k = 0; k < IN_SIZE; ++k) f[k] = 0.0f;
    }

    // ---- prologue: a_in[t] = bias + x_t . wih_row + onehot-weight (per lane) ----
    float ain[TSTEPS];
#pragma unroll
    for (int t = 0; t < TSTEPS; ++t) {
        const int eat = __builtin_amdgcn_readlane(ea, t);   // uniform
        const float w1 = W_ih[row * FEAT + IN_SIZE + eat];  // L1-hot (4.6 KB)
        float a = bias + ((t < cnt) ? w1 : 0.0f);
#pragma unroll
        for (int k = 0; k < IN_SIZE; ++k)
            a = fmaf(rl(f[k], t), wih[k], a);
        ain[t] = a;
    }

    // ---- LSTM: per step 16 readlane + 16 FMA + 1 own-gate act + 3 swizzles ----
    const float sa = (r == 2) ? -2.0f : -1.0f;   // r==2 -> tanh via 2*sig(2a)-1
    const float ma = (r == 2) ?  2.0f :  1.0f;
    const float oa = (r == 2) ? -1.0f :  0.0f;

    float h = 0.0f, c = 0.0f;
#pragma unroll
    for (int t = 0; t < TSTEPS; ++t) {
        float a;
        if (t == 0) {
            a = ain[0];
        } else {
            float A0 = ain[t], A1 = 0.0f, A2 = 0.0f, A3 = 0.0f;
#pragma unroll
            for (int v = 0; v < HID; v += 4) {
                A0 = fmaf(rl(h, v + 0), whh[v + 0], A0);
                A1 = fmaf(rl(h, v + 1), whh[v + 1], A1);
                A2 = fmaf(rl(h, v + 2), whh[v + 2], A2);
                A3 = fmaf(rl(h, v + 3), whh[v + 3], A3);
            }
            a = (A0 + A1) + (A2 + A3);
        }
        const float act = fmaf(ma, fast_rcp(1.0f + __expf(sa * a)), oa);
        const float s1 = __shfl_xor(act, 16, 64);   // sigma(f)
        const float s2 = __shfl_xor(act, 32, 64);   // tanh(g)
        const float s3 = __shfl_xor(s1, 32, 64);    // sigma(o)
        c = fmaf(s1, c, act * s2);                  // lanes 0..15 valid
        const float th = fmaf(2.0f, fast_rcp(1.0f + __expf(-2.0f * c)), -1.0f);
        h = s3 * th;
    }

    // ---- fc epilogue ----
    const float hb = __shfl(h, u, 64);              // lane wl <- h[u] from lane u
    float p = hb * wfc;                             // W_fc[r][u] == W_fc[row]
#pragma unroll
    for (int m = 8; m >= 1; m >>= 1) p += __shfl_xor(p, m, 16);
    if (u == 0 && g < B) out[g * 4 + r] = p + bfc;
}

extern "C" void kernel_launch(void* const* d_in, const int* in_sizes, int n_in,
                              void* d_out, int out_size, void* d_ws, size_t ws_size,
                              hipStream_t stream) {
    const float* x     = (const float*)d_in[0];
    const float* W_ih  = (const float*)d_in[1];
    const float* W_hh  = (const float*)d_in[2];
    const float* b_ih  = (const float*)d_in[3];
    const float* b_hh  = (const float*)d_in[4];
    const float* W_fc  = (const float*)d_in[5];
    const float* b_fc  = (const float*)d_in[6];
    const int* edge_index = (const int*)d_in[7];
    const int* edge_attr  = (const int*)d_in[8];
    const int* batch      = (const int*)d_in[9];

    const int E = in_sizes[8];            // N_EDGES
    const int B = out_size / 4;           // N_GRAPHS
    const int S = (E + SSTRIDE - 1) / SSTRIDE;   // 62500 for E=8M

    int* tbl = (int*)d_ws;                // 250 KB in workspace

    sample_batch<<<(S + 255) / 256, 256, 0, stream>>>(batch, tbl, E, S);

    const int grid = (B + 3) / 4;         // 4 graphs (waves) per 256-thread block
    tgnn_lstm_fused<<<grid, 256, 0, stream>>>(x, W_ih, W_hh, b_ih, b_hh,
                                              W_fc, b_fc,
                                              edge_index, edge_attr, batch, tbl,
                                              (float*)d_out, E, B, S);
}

// Round 8
// 27.185 us; speedup vs baseline: 1.0269x; 1.0269x over previous
//
#include <hip/hip_runtime.h>

#define IN_SIZE 11
#define HID 16
#define FEAT 18
#define TSTEPS 18

__device__ __forceinline__ float fast_rcp(float v) { return __builtin_amdgcn_rcpf(v); }

// broadcast a float from a fixed lane via v_readlane (SGPR path, no DS)
__device__ __forceinline__ float rl(float v, int lane) {
    return __int_as_float(__builtin_amdgcn_readlane(__float_as_int(v), lane));
}

// ---------------------------------------------------------------------------
// Kernel A: coalesced rise-scan of sorted batch[] -> first_arr[0..B].
// Thread t owns 16 elements [16t, 16t+16): 4x int4 loads + 1 scalar prev.
// A rise batch[j] > batch[j-1] writes first_arr[v] = j for v in
// (batch[j-1], batch[j]]  (each of the B+1 entries written exactly once).
// No shfl, no pack gather, stores only on the rare rise path.
// ---------------------------------------------------------------------------
__global__ __launch_bounds__(256)
void scan_bounds(const int* __restrict__ batch, int* __restrict__ first_arr,
                 int E, int B)
{
    const long long t = blockIdx.x * (long long)blockDim.x + threadIdx.x;
    const long long base = t * 16;
    if (base >= E) return;
    const int prev = (base == 0) ? -1 : batch[base - 1];

    if (base + 16 <= E) {
        const int4* bp = reinterpret_cast<const int4*>(batch + base);
        const int4 q0 = bp[0], q1 = bp[1], q2 = bp[2], q3 = bp[3];
        if (q3.w > prev) {                       // rare: any rise in this chunk
            int v[17];
            v[0] = prev;
            v[1]  = q0.x; v[2]  = q0.y; v[3]  = q0.z; v[4]  = q0.w;
            v[5]  = q1.x; v[6]  = q1.y; v[7]  = q1.z; v[8]  = q1.w;
            v[9]  = q2.x; v[10] = q2.y; v[11] = q2.z; v[12] = q2.w;
            v[13] = q3.x; v[14] = q3.y; v[15] = q3.z; v[16] = q3.w;
#pragma unroll
            for (int s = 1; s <= 16; ++s) {
                if (v[s] > v[s - 1]) {
                    const int j = (int)base + s - 1;
                    for (int g2 = v[s - 1] + 1; g2 <= v[s]; ++g2)
                        first_arr[g2] = j;
                }
            }
        }
    } else {
        // partial last chunk (E % 16 != 0): scalar walk
        int pv = prev;
        for (long long j = base; j < E; ++j) {
            const int bv = batch[j];
            if (bv > pv)
                for (int g2 = pv + 1; g2 <= bv; ++g2) first_arr[g2] = (int)j;
            pv = bv;
        }
    }
    // tail: values above batch[E-1] (owner: thread whose chunk contains E-1)
    if (base + 16 >= E) {
        const int bl = batch[E - 1];
        for (int g2 = bl + 1; g2 <= B; ++g2) first_arr[g2] = E;
    }
}

// ---------------------------------------------------------------------------
// Main kernel: one WAVE per graph (r6 body, search replaced by table reads).
// Lane wl owns gate row wl (r=wl>>4, u=wl&15).
// ---------------------------------------------------------------------------
extern "C" __global__ __launch_bounds__(256, 4)
void tgnn_lstm_main(const float* __restrict__ x,
                    const float* __restrict__ W_ih,
                    const float* __restrict__ W_hh,
                    const float* __restrict__ b_ih,
                    const float* __restrict__ b_hh,
                    const float* __restrict__ W_fc,
                    const float* __restrict__ b_fc,
                    const int* __restrict__ edge_index,
                    const int* __restrict__ edge_attr,
                    const int* __restrict__ first_arr,
                    float* __restrict__ out,
                    int E, int B)
{
    const int wl  = threadIdx.x & 63;
    const int g   = (blockIdx.x * blockDim.x + threadIdx.x) >> 6;  // wave = graph
    const int u   = wl & 15;
    const int r   = wl >> 4;
    const int row = wl;

    // ---- per-lane weights (issued first; latency overlaps boundary reads) ----
    float wih[IN_SIZE], whh[HID];
#pragma unroll
    for (int k = 0; k < IN_SIZE; ++k) wih[k] = W_ih[row * FEAT + k];
#pragma unroll
    for (int v = 0; v < HID; ++v) whh[v] = W_hh[row * HID + v];
    const float bias = b_ih[row] + b_hh[row];
    const float wfc  = W_fc[row];
    const float bfc  = b_fc[r];

    // ---- boundaries: one 16 KB table, hot everywhere (one latency round) ----
    const int f0 = first_arr[g];
    const int f1 = first_arr[g + 1];
    int cnt = f1 - f0;
    cnt = (cnt < 0) ? 0 : ((cnt > TSTEPS) ? TSTEPS : cnt);

    // ---- edge fetch: lane t (t<18) loads step t's ids + attr (one round) ----
    int n1 = 0, n2 = 0, ea = 0;
    if (wl < TSTEPS) {
        int j = f0 + wl;
        if (j > E - 1) j = E - 1;
        n1 = edge_index[j];
        n2 = edge_index[E + j];
        ea = edge_attr[j];               // in [0,7) even when clamped
    }

    // ---- x gather: lane t holds step t's 11 summed features (one round) ----
    float f[IN_SIZE];
    {
        const float* xa = x + (long)n1 * IN_SIZE;
        const float* xb = x + (long)n2 * IN_SIZE;
#pragma unroll
        for (int k = 0; k < IN_SIZE; ++k) f[k] = xa[k] + xb[k];
    }
    if (wl >= cnt) {                     // invalid steps AND lanes >= 18
#pragma unroll
        for (int k = 0; k < IN_SIZE; ++k) f[k] = 0.0f;
    }

    // ---- prologue: a_in[t] = bias + x_t . wih_row + onehot-weight (per lane) ----
    float ain[TSTEPS];
#pragma unroll
    for (int t = 0; t < TSTEPS; ++t) {
        const int eat = __builtin_amdgcn_readlane(ea, t);   // uniform
        const float w1 = W_ih[row * FEAT + IN_SIZE + eat];  // L1-hot (4.6 KB)
        float a = bias + ((t < cnt) ? w1 : 0.0f);
#pragma unroll
        for (int k = 0; k < IN_SIZE; ++k)
            a = fmaf(rl(f[k], t), wih[k], a);
        ain[t] = a;
    }

    // ---- LSTM: per step 16 readlane + 16 FMA + 1 own-gate act + 3 swizzles ----
    const float sa = (r == 2) ? -2.0f : -1.0f;   // r==2 -> tanh via 2*sig(2a)-1
    const float ma = (r == 2) ?  2.0f :  1.0f;
    const float oa = (r == 2) ? -1.0f :  0.0f;

    float h = 0.0f, c = 0.0f;
#pragma unroll
    for (int t = 0; t < TSTEPS; ++t) {
        float a;
        if (t == 0) {
            a = ain[0];
        } else {
            float A0 = ain[t], A1 = 0.0f, A2 = 0.0f, A3 = 0.0f;
#pragma unroll
            for (int v = 0; v < HID; v += 4) {
                A0 = fmaf(rl(h, v + 0), whh[v + 0], A0);
                A1 = fmaf(rl(h, v + 1), whh[v + 1], A1);
                A2 = fmaf(rl(h, v + 2), whh[v + 2], A2);
                A3 = fmaf(rl(h, v + 3), whh[v + 3], A3);
            }
            a = (A0 + A1) + (A2 + A3);
        }
        const float act = fmaf(ma, fast_rcp(1.0f + __expf(sa * a)), oa);
        const float s1 = __shfl_xor(act, 16, 64);   // sigma(f)
        const float s2 = __shfl_xor(act, 32, 64);   // tanh(g)
        const float s3 = __shfl_xor(s1, 32, 64);    // sigma(o)
        c = fmaf(s1, c, act * s2);                  // lanes 0..15 valid
        const float th = fmaf(2.0f, fast_rcp(1.0f + __expf(-2.0f * c)), -1.0f);
        h = s3 * th;
    }

    // ---- fc epilogue ----
    const float hb = __shfl(h, u, 64);              // lane wl <- h[u] from lane u
    float p = hb * wfc;                             // W_fc[r][u] == W_fc[row]
#pragma unroll
    for (int m = 8; m >= 1; m >>= 1) p += __shfl_xor(p, m, 16);
    if (u == 0 && g < B) out[g * 4 + r] = p + bfc;
}

extern "C" void kernel_launch(void* const* d_in, const int* in_sizes, int n_in,
                              void* d_out, int out_size, void* d_ws, size_t ws_size,
                              hipStream_t stream) {
    const float* x     = (const float*)d_in[0];
    const float* W_ih  = (const float*)d_in[1];
    const float* W_hh  = (const float*)d_in[2];
    const float* b_ih  = (const float*)d_in[3];
    const float* b_hh  = (const float*)d_in[4];
    const float* W_fc  = (const float*)d_in[5];
    const float* b_fc  = (const float*)d_in[6];
    const int* edge_index = (const int*)d_in[7];
    const int* edge_attr  = (const int*)d_in[8];
    const int* batch      = (const int*)d_in[9];

    const int E = in_sizes[8];            // N_EDGES
    const int B = out_size / 4;           // N_GRAPHS

    int* first_arr = (int*)d_ws;          // (B+1) ints = 16.4 KB

    const int nthr  = (E + 15) / 16;      // one thread per 16 elements
    const int sgrid = (nthr + 255) / 256;
    scan_bounds<<<sgrid, 256, 0, stream>>>(batch, first_arr, E, B);

    const int grid = (B + 3) / 4;         // 4 graphs (waves) per 256-thread block
    tgnn_lstm_main<<<grid, 256, 0, stream>>>(x, W_ih, W_hh, b_ih, b_hh,
                                             W_fc, b_fc,
                                             edge_index, edge_attr, first_arr,
                                             (float*)d_out, E, B);
}